// Round 1
// baseline (831.827 us; speedup 1.0000x reference)
//
#include <hip/hip_runtime.h>

// Problem constants (match reference)
#define Bdim 4
#define Cdim 32
#define Hdim 512
#define Wdim 512
#define HWdim (Hdim * Wdim)

__global__ __launch_bounds__(256) void warp_add_kernel(
    const float* __restrict__ x,
    const float* __restrict__ flow,
    const float* __restrict__ residual,
    float* __restrict__ out)
{
    int tid = blockIdx.x * blockDim.x + threadIdx.x;   // over B*H*W
    // grid exactly covers B*H*W (power of two), no bounds check needed
    int w = tid & (Wdim - 1);
    int h = (tid >> 9) & (Hdim - 1);
    int b = tid >> 18;

    // flow: [B, 2, H, W]
    const float fx = flow[((size_t)b * 2 + 0) * HWdim + h * Wdim + w];
    const float fy = flow[((size_t)b * 2 + 1) * HWdim + h * Wdim + w];

    // align_corners=False pixel-center grid in [-1,1]
    float gx = ((float)w + 0.5f) * (2.0f / (float)Wdim) - 1.0f + fx;
    float gy = ((float)h + 0.5f) * (2.0f / (float)Hdim) - 1.0f + fy;

    // circular wrap on x only: gx = mod(gx + 1, 2) - 1   (jnp.mod: result in [0,2))
    {
        float t = fmodf(gx + 1.0f, 2.0f);
        if (t < 0.0f) t += 2.0f;
        gx = t - 1.0f;
    }

    const float real_x = (gx + 1.0f) * ((float)Wdim * 0.5f) - 0.5f;
    const float real_y = (gy + 1.0f) * ((float)Hdim * 0.5f) - 0.5f;

    const float x0f = floorf(real_x);
    const float y0f = floorf(real_y);
    const float dx = real_x - x0f;
    const float dy = real_y - y0f;

    const int ix0 = (int)x0f;
    const int iy0 = (int)y0f;
    const int ix1 = ix0 + 1;
    const int iy1 = iy0 + 1;

    const bool vx0 = (ix0 >= 0) && (ix0 < Wdim);
    const bool vx1 = (ix1 >= 0) && (ix1 < Wdim);
    const bool vy0 = (iy0 >= 0) && (iy0 < Hdim);
    const bool vy1 = (iy1 >= 0) && (iy1 < Hdim);

    // clamped indices (gather address always in-bounds; invalid corners get weight 0)
    const int cx0 = min(max(ix0, 0), Wdim - 1);
    const int cx1 = min(max(ix1, 0), Wdim - 1);
    const int cy0 = min(max(iy0, 0), Hdim - 1);
    const int cy1 = min(max(iy1, 0), Hdim - 1);

    float w_tl = (1.0f - dx) * (1.0f - dy);
    float w_tr = dx * (1.0f - dy);
    float w_bl = (1.0f - dx) * dy;
    float w_br = dx * dy;
    if (!(vx0 && vy0)) w_tl = 0.0f;
    if (!(vx1 && vy0)) w_tr = 0.0f;
    if (!(vx0 && vy1)) w_bl = 0.0f;
    if (!(vx1 && vy1)) w_br = 0.0f;

    const int off_tl = cy0 * Wdim + cx0;
    const int off_tr = cy0 * Wdim + cx1;
    const int off_bl = cy1 * Wdim + cx0;
    const int off_br = cy1 * Wdim + cx1;

    const size_t base = (size_t)b * Cdim * HWdim;
    const int    pix  = h * Wdim + w;
    const float* xb = x + base;
    const float* rb = residual + base + pix;
    float*       ob = out + base + pix;

    #pragma unroll 8
    for (int c = 0; c < Cdim; ++c) {
        const float* xc = xb + (size_t)c * HWdim;
        float v = w_tl * xc[off_tl]
                + w_tr * xc[off_tr]
                + w_bl * xc[off_bl]
                + w_br * xc[off_br]
                + rb[(size_t)c * HWdim];
        ob[(size_t)c * HWdim] = v;
    }
}

extern "C" void kernel_launch(void* const* d_in, const int* in_sizes, int n_in,
                              void* d_out, int out_size, void* d_ws, size_t ws_size,
                              hipStream_t stream) {
    const float* x        = (const float*)d_in[0];
    const float* flow     = (const float*)d_in[1];
    const float* residual = (const float*)d_in[2];
    float* out            = (float*)d_out;

    const int total = Bdim * Hdim * Wdim;      // 1,048,576 threads
    const int block = 256;
    const int grid  = total / block;           // 4096 blocks
    warp_add_kernel<<<grid, block, 0, stream>>>(x, flow, residual, out);
}

// Round 2
// 380.616 us; speedup vs baseline: 2.1855x; 2.1855x over previous
//
#include <hip/hip_runtime.h>

// Problem constants (match reference)
#define Bdim 4
#define Cdim 32
#define Hdim 512
#define Wdim 512
#define HWdim (Hdim * Wdim)

typedef __attribute__((ext_vector_type(2))) float f32x2;
typedef __attribute__((ext_vector_type(4))) float f32x4;

// ---------------------------------------------------------------------------
// Kernel A: transpose x [B][C][H][W] -> ws NHWC [B][H][W][C]
// One block: 256 threads handle (b, h) fixed, 64-wide w strip, all 32 c.
// ---------------------------------------------------------------------------
__global__ __launch_bounds__(256) void transpose_nhwc_kernel(
    const float* __restrict__ x, float* __restrict__ ws)
{
    __shared__ float lds[Cdim * 65];   // [c][w] padded: 32 x 65

    const int idx = blockIdx.x;               // 16384 blocks
    const int tw  = idx & 7;                  // W/64 = 8 strips
    const int h   = (idx >> 3) & (Hdim - 1);
    const int b   = idx >> 12;
    const int w0  = tw * 64;

    const int t  = threadIdx.x;
    const int wi = t & 63;
    const int cg = t >> 6;                    // 0..3, covers 8 channels each

    // read coalesced: for each c, 64 consecutive w
    #pragma unroll
    for (int i = 0; i < 8; ++i) {
        const int c = cg * 8 + i;
        const float v = x[(((size_t)b * Cdim + c) * Hdim + h) * Wdim + w0 + wi];
        lds[c * 65 + wi] = v;
    }
    __syncthreads();

    // write: 2048 consecutive floats from base; thread t writes [t*8, t*8+8)
    const size_t base = (((size_t)b * Hdim + h) * Wdim + w0) * Cdim;
    const int w_  = t >> 2;            // (t*8)>>5
    const int c0  = (t & 3) * 8;       // (t*8)&31
    f32x4 v0, v1;
    #pragma unroll
    for (int k = 0; k < 4; ++k) v0[k] = lds[(c0 + k) * 65 + w_];
    #pragma unroll
    for (int k = 0; k < 4; ++k) v1[k] = lds[(c0 + 4 + k) * 65 + w_];
    f32x4* dst = (f32x4*)(ws + base + (size_t)t * 8);
    dst[0] = v0;
    dst[1] = v1;
}

// ---------------------------------------------------------------------------
// Kernel B: gather from NHWC ws + residual -> out (NCHW)
// Block = 256 threads <-> 256 consecutive pixels of one row (b, h, w0..w0+255).
// Phase 1: per-pixel flow math -> LDS (offsets into NHWC batch slice, weights)
// Phase 2: lanes span channels: thread (ci = t&15 -> 2 channels, p = t>>4
//          -> 16 pixels). Each corner gather: 16 lanes x float2 = one fully
//          used 128B segment. Accumulate, stash in LDS buf[c][pix].
// Phase 3: transpose out of LDS, add residual, coalesced NCHW store.
// ---------------------------------------------------------------------------
__global__ __launch_bounds__(256) void gather_nhwc_kernel(
    const float* __restrict__ ws,
    const float* __restrict__ flow,
    const float* __restrict__ residual,
    float* __restrict__ out)
{
    __shared__ int   s_off[4][256];
    __shared__ float s_wt[4][256];
    __shared__ float s_buf[Cdim][257];   // [c][pix] padded

    const int idx = blockIdx.x;                 // 4096 blocks
    const int b   = idx >> 10;
    const int h   = (idx >> 1) & (Hdim - 1);
    const int w0  = (idx & 1) << 8;
    const int t   = threadIdx.x;

    // ---- Phase 1: per-pixel sampling math (identical numerics to R1) ----
    {
        const int w = w0 + t;
        const int pixg = h * Wdim + w;
        const float fx = flow[((size_t)b * 2 + 0) * HWdim + pixg];
        const float fy = flow[((size_t)b * 2 + 1) * HWdim + pixg];

        float gx = ((float)w + 0.5f) * (2.0f / (float)Wdim) - 1.0f + fx;
        float gy = ((float)h + 0.5f) * (2.0f / (float)Hdim) - 1.0f + fy;

        float tm = fmodf(gx + 1.0f, 2.0f);
        if (tm < 0.0f) tm += 2.0f;
        gx = tm - 1.0f;

        const float real_x = (gx + 1.0f) * ((float)Wdim * 0.5f) - 0.5f;
        const float real_y = (gy + 1.0f) * ((float)Hdim * 0.5f) - 0.5f;

        const float x0f = floorf(real_x);
        const float y0f = floorf(real_y);
        const float dx = real_x - x0f;
        const float dy = real_y - y0f;

        const int ix0 = (int)x0f;
        const int iy0 = (int)y0f;
        const int ix1 = ix0 + 1;
        const int iy1 = iy0 + 1;

        const bool vx0 = (ix0 >= 0) && (ix0 < Wdim);
        const bool vx1 = (ix1 >= 0) && (ix1 < Wdim);
        const bool vy0 = (iy0 >= 0) && (iy0 < Hdim);
        const bool vy1 = (iy1 >= 0) && (iy1 < Hdim);

        const int cx0 = min(max(ix0, 0), Wdim - 1);
        const int cx1 = min(max(ix1, 0), Wdim - 1);
        const int cy0 = min(max(iy0, 0), Hdim - 1);
        const int cy1 = min(max(iy1, 0), Hdim - 1);

        float w_tl = (1.0f - dx) * (1.0f - dy);
        float w_tr = dx * (1.0f - dy);
        float w_bl = (1.0f - dx) * dy;
        float w_br = dx * dy;
        if (!(vx0 && vy0)) w_tl = 0.0f;
        if (!(vx1 && vy0)) w_tr = 0.0f;
        if (!(vx0 && vy1)) w_bl = 0.0f;
        if (!(vx1 && vy1)) w_br = 0.0f;

        s_off[0][t] = (cy0 * Wdim + cx0) * Cdim;
        s_off[1][t] = (cy0 * Wdim + cx1) * Cdim;
        s_off[2][t] = (cy1 * Wdim + cx0) * Cdim;
        s_off[3][t] = (cy1 * Wdim + cx1) * Cdim;
        s_wt[0][t] = w_tl;
        s_wt[1][t] = w_tr;
        s_wt[2][t] = w_bl;
        s_wt[3][t] = w_br;
    }
    __syncthreads();

    // ---- Phase 2: coalesced channel-major gather ----
    {
        const int ci = t & 15;          // channel pair index: channels 2ci, 2ci+1
        const int p  = t >> 4;          // pixel group 0..15
        const int c0 = ci * 2;
        const float* xb = ws + (size_t)b * HWdim * Cdim + c0;

        #pragma unroll 4
        for (int j = 0; j < 16; ++j) {
            const int pix = p * 16 + j;
            const int o0 = s_off[0][pix];
            const int o1 = s_off[1][pix];
            const int o2 = s_off[2][pix];
            const int o3 = s_off[3][pix];
            const float w0_ = s_wt[0][pix];
            const float w1_ = s_wt[1][pix];
            const float w2_ = s_wt[2][pix];
            const float w3_ = s_wt[3][pix];

            const f32x2 v0 = *(const f32x2*)(xb + o0);
            const f32x2 v1 = *(const f32x2*)(xb + o1);
            const f32x2 v2 = *(const f32x2*)(xb + o2);
            const f32x2 v3 = *(const f32x2*)(xb + o3);

            f32x2 acc = w0_ * v0 + w1_ * v1 + w2_ * v2 + w3_ * v3;
            s_buf[c0][pix]     = acc.x;
            s_buf[c0 + 1][pix] = acc.y;
        }
    }
    __syncthreads();

    // ---- Phase 3: coalesced NCHW store + residual ----
    {
        const size_t pbase = (size_t)h * Wdim + w0 + t;
        #pragma unroll 8
        for (int cc = 0; cc < Cdim; ++cc) {
            const size_t gi = ((size_t)b * Cdim + cc) * HWdim + pbase;
            const float r = __builtin_nontemporal_load(residual + gi);
            __builtin_nontemporal_store(s_buf[cc][t] + r, out + gi);
        }
    }
}

// ---------------------------------------------------------------------------
// Fallback (R1 kernel) if workspace is too small for the NHWC intermediate
// ---------------------------------------------------------------------------
__global__ __launch_bounds__(256) void warp_add_kernel(
    const float* __restrict__ x,
    const float* __restrict__ flow,
    const float* __restrict__ residual,
    float* __restrict__ out)
{
    int tid = blockIdx.x * blockDim.x + threadIdx.x;
    int w = tid & (Wdim - 1);
    int h = (tid >> 9) & (Hdim - 1);
    int b = tid >> 18;

    const float fx = flow[((size_t)b * 2 + 0) * HWdim + h * Wdim + w];
    const float fy = flow[((size_t)b * 2 + 1) * HWdim + h * Wdim + w];

    float gx = ((float)w + 0.5f) * (2.0f / (float)Wdim) - 1.0f + fx;
    float gy = ((float)h + 0.5f) * (2.0f / (float)Hdim) - 1.0f + fy;
    {
        float t2 = fmodf(gx + 1.0f, 2.0f);
        if (t2 < 0.0f) t2 += 2.0f;
        gx = t2 - 1.0f;
    }
    const float real_x = (gx + 1.0f) * ((float)Wdim * 0.5f) - 0.5f;
    const float real_y = (gy + 1.0f) * ((float)Hdim * 0.5f) - 0.5f;
    const float x0f = floorf(real_x);
    const float y0f = floorf(real_y);
    const float dx = real_x - x0f;
    const float dy = real_y - y0f;
    const int ix0 = (int)x0f, iy0 = (int)y0f;
    const int ix1 = ix0 + 1,  iy1 = iy0 + 1;
    const bool vx0 = (ix0 >= 0) && (ix0 < Wdim);
    const bool vx1 = (ix1 >= 0) && (ix1 < Wdim);
    const bool vy0 = (iy0 >= 0) && (iy0 < Hdim);
    const bool vy1 = (iy1 >= 0) && (iy1 < Hdim);
    const int cx0 = min(max(ix0, 0), Wdim - 1);
    const int cx1 = min(max(ix1, 0), Wdim - 1);
    const int cy0 = min(max(iy0, 0), Hdim - 1);
    const int cy1 = min(max(iy1, 0), Hdim - 1);
    float w_tl = (1.0f - dx) * (1.0f - dy);
    float w_tr = dx * (1.0f - dy);
    float w_bl = (1.0f - dx) * dy;
    float w_br = dx * dy;
    if (!(vx0 && vy0)) w_tl = 0.0f;
    if (!(vx1 && vy0)) w_tr = 0.0f;
    if (!(vx0 && vy1)) w_bl = 0.0f;
    if (!(vx1 && vy1)) w_br = 0.0f;
    const int off_tl = cy0 * Wdim + cx0;
    const int off_tr = cy0 * Wdim + cx1;
    const int off_bl = cy1 * Wdim + cx0;
    const int off_br = cy1 * Wdim + cx1;
    const size_t base = (size_t)b * Cdim * HWdim;
    const int    pix  = h * Wdim + w;
    const float* xb = x + base;
    const float* rb = residual + base + pix;
    float*       ob = out + base + pix;
    #pragma unroll 8
    for (int c = 0; c < Cdim; ++c) {
        const float* xc = xb + (size_t)c * HWdim;
        float v = w_tl * xc[off_tl] + w_tr * xc[off_tr]
                + w_bl * xc[off_bl] + w_br * xc[off_br]
                + rb[(size_t)c * HWdim];
        ob[(size_t)c * HWdim] = v;
    }
}

extern "C" void kernel_launch(void* const* d_in, const int* in_sizes, int n_in,
                              void* d_out, int out_size, void* d_ws, size_t ws_size,
                              hipStream_t stream) {
    const float* x        = (const float*)d_in[0];
    const float* flow     = (const float*)d_in[1];
    const float* residual = (const float*)d_in[2];
    float* out            = (float*)d_out;

    const size_t ws_needed = (size_t)Bdim * Cdim * HWdim * sizeof(float); // 128 MiB

    if (ws_size >= ws_needed) {
        float* ws = (float*)d_ws;
        transpose_nhwc_kernel<<<Bdim * Hdim * (Wdim / 64), 256, 0, stream>>>(x, ws);
        gather_nhwc_kernel<<<Bdim * Hdim * Wdim / 256, 256, 0, stream>>>(ws, flow, residual, out);
    } else {
        const int total = Bdim * Hdim * Wdim;
        warp_add_kernel<<<total / 256, 256, 0, stream>>>(x, flow, residual, out);
    }
}

// Round 3
// 349.045 us; speedup vs baseline: 2.3832x; 1.0904x over previous
//
#include <hip/hip_runtime.h>

// Problem constants (match reference)
#define Bdim 4
#define Cdim 32
#define Hdim 512
#define Wdim 512
#define HWdim (Hdim * Wdim)

typedef __attribute__((ext_vector_type(2))) float    f32x2;
typedef __attribute__((ext_vector_type(4))) float    f32x4;
typedef __attribute__((ext_vector_type(2))) _Float16 f16x2;
typedef __attribute__((ext_vector_type(4))) _Float16 f16x4;
typedef __attribute__((ext_vector_type(8))) _Float16 f16x8;

// ---------------------------------------------------------------------------
// Kernel A: transpose x [B][C][H][W] (fp32) -> ws NHWC [B][H][W][C] (fp16)
// One block: (b, h) fixed, 64-wide w strip, all 32 c.
// ---------------------------------------------------------------------------
__global__ __launch_bounds__(256) void transpose_nhwc_half_kernel(
    const float* __restrict__ x, _Float16* __restrict__ ws)
{
    __shared__ float lds[Cdim * 65];   // [c][w] padded: 32 x 65 floats

    const int idx = blockIdx.x;               // 16384 blocks
    const int tw  = idx & 7;                  // W/64 = 8 strips
    const int h   = (idx >> 3) & (Hdim - 1);
    const int b   = idx >> 12;
    const int w0  = tw * 64;

    const int t  = threadIdx.x;
    const int wi = t & 63;
    const int cg = t >> 6;                    // 0..3, 8 channels each

    #pragma unroll
    for (int i = 0; i < 8; ++i) {
        const int c = cg * 8 + i;
        lds[c * 65 + wi] = x[(((size_t)b * Cdim + c) * Hdim + h) * Wdim + w0 + wi];
    }
    __syncthreads();

    // output block = 2048 halves contiguous; thread t writes halves [t*8, t*8+8)
    const size_t base = (((size_t)b * Hdim + h) * Wdim + w0) * Cdim;
    const int w_ = t >> 2;             // local w
    const int c0 = (t & 3) * 8;        // first channel
    f16x8 v;
    #pragma unroll
    for (int k = 0; k < 8; ++k) v[k] = (_Float16)lds[(c0 + k) * 65 + w_];
    *(f16x8*)(ws + base + (size_t)t * 8) = v;   // 16B store, wave = 1KB contiguous
}

// ---------------------------------------------------------------------------
// Kernel B: gather from NHWC fp16 ws + residual -> out (NCHW fp32)
// Block = 256 consecutive pixels of one row (b, h, w0..w0+255).
// Phase 1: per-pixel flow math -> LDS (NHWC half offsets, fp32 weights)
// Phase 2: 8 lanes per pixel, 4 channels each (f16x4 = 8B per corner load;
//          8 lanes x 8B = 64B fully-used segment). fp32 accumulate,
//          stash fp16 into s_buf[pix][c] (stride 34 -> <=2-way banks).
// Phase 3: read s_buf row, add residual, coalesced NCHW nontemporal store.
// ---------------------------------------------------------------------------
__global__ __launch_bounds__(256) void gather_nhwc_half_kernel(
    const _Float16* __restrict__ ws,
    const float* __restrict__ flow,
    const float* __restrict__ residual,
    float* __restrict__ out)
{
    __shared__ int      s_off[4][256];
    __shared__ float    s_wt[4][256];
    __shared__ _Float16 s_buf[256 * 34];   // [pix][c], stride 34 halves (8B-aligned rows? pix*34*2B = 68B -> 4B aligned; half2 ops only)

    const int idx = blockIdx.x;                 // 4096 blocks
    const int b   = idx >> 10;
    const int h   = (idx >> 1) & (Hdim - 1);
    const int w0  = (idx & 1) << 8;
    const int t   = threadIdx.x;

    // ---- Phase 1: per-pixel sampling math (numerics identical to R1/R2) ----
    {
        const int w = w0 + t;
        const int pixg = h * Wdim + w;
        const float fx = flow[((size_t)b * 2 + 0) * HWdim + pixg];
        const float fy = flow[((size_t)b * 2 + 1) * HWdim + pixg];

        float gx = ((float)w + 0.5f) * (2.0f / (float)Wdim) - 1.0f + fx;
        float gy = ((float)h + 0.5f) * (2.0f / (float)Hdim) - 1.0f + fy;

        float tm = fmodf(gx + 1.0f, 2.0f);
        if (tm < 0.0f) tm += 2.0f;
        gx = tm - 1.0f;

        const float real_x = (gx + 1.0f) * ((float)Wdim * 0.5f) - 0.5f;
        const float real_y = (gy + 1.0f) * ((float)Hdim * 0.5f) - 0.5f;

        const float x0f = floorf(real_x);
        const float y0f = floorf(real_y);
        const float dx = real_x - x0f;
        const float dy = real_y - y0f;

        const int ix0 = (int)x0f;
        const int iy0 = (int)y0f;
        const int ix1 = ix0 + 1;
        const int iy1 = iy0 + 1;

        const bool vx0 = (ix0 >= 0) && (ix0 < Wdim);
        const bool vx1 = (ix1 >= 0) && (ix1 < Wdim);
        const bool vy0 = (iy0 >= 0) && (iy0 < Hdim);
        const bool vy1 = (iy1 >= 0) && (iy1 < Hdim);

        const int cx0 = min(max(ix0, 0), Wdim - 1);
        const int cx1 = min(max(ix1, 0), Wdim - 1);
        const int cy0 = min(max(iy0, 0), Hdim - 1);
        const int cy1 = min(max(iy1, 0), Hdim - 1);

        float w_tl = (1.0f - dx) * (1.0f - dy);
        float w_tr = dx * (1.0f - dy);
        float w_bl = (1.0f - dx) * dy;
        float w_br = dx * dy;
        if (!(vx0 && vy0)) w_tl = 0.0f;
        if (!(vx1 && vy0)) w_tr = 0.0f;
        if (!(vx0 && vy1)) w_bl = 0.0f;
        if (!(vx1 && vy1)) w_br = 0.0f;

        s_off[0][t] = (cy0 * Wdim + cx0) * Cdim;   // offsets in halves
        s_off[1][t] = (cy0 * Wdim + cx1) * Cdim;
        s_off[2][t] = (cy1 * Wdim + cx0) * Cdim;
        s_off[3][t] = (cy1 * Wdim + cx1) * Cdim;
        s_wt[0][t] = w_tl;
        s_wt[1][t] = w_tr;
        s_wt[2][t] = w_bl;
        s_wt[3][t] = w_br;
    }
    __syncthreads();

    // ---- Phase 2: coalesced channel-major gather ----
    {
        const int ci = t & 7;          // channel quad: channels 4ci..4ci+3
        const int c0 = ci * 4;
        const int p  = t >> 3;         // 0..31 pixel slot
        const _Float16* xb = ws + (size_t)b * HWdim * Cdim + c0;

        #pragma unroll 4
        for (int j = 0; j < 8; ++j) {
            const int pix = j * 32 + p;
            const int o0 = s_off[0][pix];
            const int o1 = s_off[1][pix];
            const int o2 = s_off[2][pix];
            const int o3 = s_off[3][pix];
            const float w0_ = s_wt[0][pix];
            const float w1_ = s_wt[1][pix];
            const float w2_ = s_wt[2][pix];
            const float w3_ = s_wt[3][pix];

            const f16x4 v0 = *(const f16x4*)(xb + o0);   // 8B load
            const f16x4 v1 = *(const f16x4*)(xb + o1);
            const f16x4 v2 = *(const f16x4*)(xb + o2);
            const f16x4 v3 = *(const f16x4*)(xb + o3);

            float a0 = w0_ * (float)v0[0] + w1_ * (float)v1[0] + w2_ * (float)v2[0] + w3_ * (float)v3[0];
            float a1 = w0_ * (float)v0[1] + w1_ * (float)v1[1] + w2_ * (float)v2[1] + w3_ * (float)v3[1];
            float a2 = w0_ * (float)v0[2] + w1_ * (float)v1[2] + w2_ * (float)v2[2] + w3_ * (float)v3[2];
            float a3 = w0_ * (float)v0[3] + w1_ * (float)v1[3] + w2_ * (float)v2[3] + w3_ * (float)v3[3];

            f16x2 h01; h01[0] = (_Float16)a0; h01[1] = (_Float16)a1;
            f16x2 h23; h23[0] = (_Float16)a2; h23[1] = (_Float16)a3;
            *(f16x2*)(s_buf + pix * 34 + c0)     = h01;  // 4B LDS stores
            *(f16x2*)(s_buf + pix * 34 + c0 + 2) = h23;
        }
    }
    __syncthreads();

    // ---- Phase 3: coalesced NCHW store + residual ----
    {
        const size_t pbase = (size_t)h * Wdim + w0 + t;
        const _Float16* row = s_buf + t * 34;
        #pragma unroll 8
        for (int cc = 0; cc < Cdim; cc += 2) {
            const f16x2 v = *(const f16x2*)(row + cc);
            const size_t gi0 = ((size_t)b * Cdim + cc) * HWdim + pbase;
            const float r0 = __builtin_nontemporal_load(residual + gi0);
            const float r1 = __builtin_nontemporal_load(residual + gi0 + HWdim);
            __builtin_nontemporal_store((float)v[0] + r0, out + gi0);
            __builtin_nontemporal_store((float)v[1] + r1, out + gi0 + HWdim);
        }
    }
}

// ---------------------------------------------------------------------------
// Fallback (R1 kernel) if workspace is too small for the NHWC fp16 buffer
// ---------------------------------------------------------------------------
__global__ __launch_bounds__(256) void warp_add_kernel(
    const float* __restrict__ x,
    const float* __restrict__ flow,
    const float* __restrict__ residual,
    float* __restrict__ out)
{
    int tid = blockIdx.x * blockDim.x + threadIdx.x;
    int w = tid & (Wdim - 1);
    int h = (tid >> 9) & (Hdim - 1);
    int b = tid >> 18;

    const float fx = flow[((size_t)b * 2 + 0) * HWdim + h * Wdim + w];
    const float fy = flow[((size_t)b * 2 + 1) * HWdim + h * Wdim + w];

    float gx = ((float)w + 0.5f) * (2.0f / (float)Wdim) - 1.0f + fx;
    float gy = ((float)h + 0.5f) * (2.0f / (float)Hdim) - 1.0f + fy;
    {
        float t2 = fmodf(gx + 1.0f, 2.0f);
        if (t2 < 0.0f) t2 += 2.0f;
        gx = t2 - 1.0f;
    }
    const float real_x = (gx + 1.0f) * ((float)Wdim * 0.5f) - 0.5f;
    const float real_y = (gy + 1.0f) * ((float)Hdim * 0.5f) - 0.5f;
    const float x0f = floorf(real_x);
    const float y0f = floorf(real_y);
    const float dx = real_x - x0f;
    const float dy = real_y - y0f;
    const int ix0 = (int)x0f, iy0 = (int)y0f;
    const int ix1 = ix0 + 1,  iy1 = iy0 + 1;
    const bool vx0 = (ix0 >= 0) && (ix0 < Wdim);
    const bool vx1 = (ix1 >= 0) && (ix1 < Wdim);
    const bool vy0 = (iy0 >= 0) && (iy0 < Hdim);
    const bool vy1 = (iy1 >= 0) && (iy1 < Hdim);
    const int cx0 = min(max(ix0, 0), Wdim - 1);
    const int cx1 = min(max(ix1, 0), Wdim - 1);
    const int cy0 = min(max(iy0, 0), Hdim - 1);
    const int cy1 = min(max(iy1, 0), Hdim - 1);
    float w_tl = (1.0f - dx) * (1.0f - dy);
    float w_tr = dx * (1.0f - dy);
    float w_bl = (1.0f - dx) * dy;
    float w_br = dx * dy;
    if (!(vx0 && vy0)) w_tl = 0.0f;
    if (!(vx1 && vy0)) w_tr = 0.0f;
    if (!(vx0 && vy1)) w_bl = 0.0f;
    if (!(vx1 && vy1)) w_br = 0.0f;
    const int off_tl = cy0 * Wdim + cx0;
    const int off_tr = cy0 * Wdim + cx1;
    const int off_bl = cy1 * Wdim + cx0;
    const int off_br = cy1 * Wdim + cx1;
    const size_t base = (size_t)b * Cdim * HWdim;
    const int    pix  = h * Wdim + w;
    const float* xb = x + base;
    const float* rb = residual + base + pix;
    float*       ob = out + base + pix;
    #pragma unroll 8
    for (int c = 0; c < Cdim; ++c) {
        const float* xc = xb + (size_t)c * HWdim;
        float v = w_tl * xc[off_tl] + w_tr * xc[off_tr]
                + w_bl * xc[off_bl] + w_br * xc[off_br]
                + rb[(size_t)c * HWdim];
        ob[(size_t)c * HWdim] = v;
    }
}

extern "C" void kernel_launch(void* const* d_in, const int* in_sizes, int n_in,
                              void* d_out, int out_size, void* d_ws, size_t ws_size,
                              hipStream_t stream) {
    const float* x        = (const float*)d_in[0];
    const float* flow     = (const float*)d_in[1];
    const float* residual = (const float*)d_in[2];
    float* out            = (float*)d_out;

    const size_t ws_needed = (size_t)Bdim * Cdim * HWdim * sizeof(_Float16); // 64 MiB

    if (ws_size >= ws_needed) {
        _Float16* ws = (_Float16*)d_ws;
        transpose_nhwc_half_kernel<<<Bdim * Hdim * (Wdim / 64), 256, 0, stream>>>(x, ws);
        gather_nhwc_half_kernel<<<Bdim * Hdim * Wdim / 256, 256, 0, stream>>>(ws, flow, residual, out);
    } else {
        const int total = Bdim * Hdim * Wdim;
        warp_add_kernel<<<total / 256, 256, 0, stream>>>(x, flow, residual, out);
    }
}